// Round 6
// baseline (28.864 us; speedup 1.0000x reference)
//
#include <hip/hip_runtime.h>
#include <math.h>

// Problem constants (match reference)
#define NB 128
#define NF 2048
#define NE 256
#define NF4 (NE / 4)   // 64 float4 per 256-float row

#define WAVES_PER_BLOCK 4
#define FACTS_PER_WAVE 32
#define FACTS_PER_BLOCK 128
#define CHUNKS_PER_B 16
#define NPASS 8                                  // 4 facts per pass, 8 passes
#define NSLOT (CHUNKS_PER_B * WAVES_PER_BLOCK)   // 64 dmin slots per b

// Branch-and-bound threshold. expf(-x) == 0.0f exactly for x > ~104
// (e^-104 < 2^-150 rounds to +0). Squared distance accumulates
// non-negatively over dims, so prefix_d > T => full d > T => score is
// exactly 0.0f in BOTH reference and ours. T=110 leaves margin: any fact
// with a nonzero score has full d <= 104 => prefix <= 104 < 110 => flagged
// and handled by the exact in-wave fallback. At this input distribution the
// 128-dim prefix ~ N(256,32): P(<=110) ~ 3e-6 per fact -> fallback ~never
// runs, but correctness never depends on that.
#define THRESH 110.0f

__device__ __forceinline__ float sqd4(float4 a, float4 b) {
    float dx = a.x - b.x;
    float dy = a.y - b.y;
    float dz = a.z - b.z;
    float dw = a.w - b.w;
    return dx * dx + dy * dy + dz * dz + dw * dw;
}

// Kernel 1: stream the first 128 floats (512 B) of each valid fact_rel row.
// 16 lanes per fact (seg = lane&15 covers float4 seg and seg+16), 4 facts
// per pass (sub = lane>>4), 8 fully-unrolled double-buffered passes = 32
// facts per wave (indices clamped to nb-1; clamped duplicates excluded from
// the candidate mask by the f<nb predicate). The wave-uniform candidate mask
// is resolved IN-WAVE: for each (ultra-rare) flagged fact, the full 768-dim
// distance is computed exactly (64 lanes x 3 float4 + 6 shuffles) and folded
// into dmin. Every wave (live or dead) writes its dmin slot -> ws fully
// rewritten every call, no init kernel, no atomics.
__global__ __launch_bounds__(256, 8) void nkb_prefix_kernel(
    const float* __restrict__ rel,
    const float* __restrict__ arg1,
    const float* __restrict__ arg2,
    const float* __restrict__ fact_rel,
    const float* __restrict__ fact_arg1,
    const float* __restrict__ fact_arg2,
    const int* __restrict__ nb_facts,
    float* __restrict__ ws)
{
    const int b = blockIdx.x >> 4;        // / CHUNKS_PER_B
    const int chunk = blockIdx.x & 15;    // % CHUNKS_PER_B
    const int nb = nb_facts[b];
    const int tid = threadIdx.x;
    const int wave = tid >> 6;
    const int lane = tid & 63;
    const int sub = lane >> 4;   // which of the 4 facts in a pass
    const int seg = lane & 15;   // float4 segment within the 128-dim prefix

    const int fbeg = chunk * FACTS_PER_BLOCK + wave * FACTS_PER_WAVE;
    float dmin = INFINITY;

    if (fbeg < nb) {
        const int fmax = nb - 1;  // nb >= 1 here
        // Query prefix: 2 float4 = 8 VGPRs (first 128 floats of rel row).
        const float4* qr = reinterpret_cast<const float4*>(rel + (size_t)b * NE);
        const float4 q0 = qr[seg];
        const float4 q1 = qr[seg + 16];

        const float4* fr = reinterpret_cast<const float4*>(fact_rel + (size_t)b * NF * NE);

        unsigned int wmask = 0;  // bit p: fact fbeg+p is a candidate (wave-uniform)
        float4 A0, A1, B0, B1;
        {
            const int f = min(fbeg + sub, fmax);
            const float4* p = fr + (size_t)f * NF4 + seg;
            A0 = p[0];
            A1 = p[16];
        }

        #pragma unroll
        for (int k = 0; k < NPASS; ++k) {
            if (k + 1 < NPASS) {  // double-buffer: next pass's loads in flight
                const int f = min(fbeg + 4 * (k + 1) + sub, fmax);
                const float4* p = fr + (size_t)f * NF4 + seg;
                B0 = p[0];
                B1 = p[16];
            }
            float acc = sqd4(q0, A0) + sqd4(q1, A1);
            // Sum within each 16-lane group: 4 facts reduced simultaneously.
            #pragma unroll
            for (int s = 1; s < 16; s <<= 1) acc += __shfl_xor(acc, s);

            const bool cand = (acc <= THRESH) && (fbeg + 4 * k + sub < nb);
            const unsigned long long bal = __ballot(cand);
            // Group j's verdict sits (replicated) at lanes 16j..16j+15.
            const unsigned int bits =
                  (unsigned int)( (bal        & 1ull)
                               | ((bal >> 16) & 1ull) << 1
                               | ((bal >> 32) & 1ull) << 2
                               | ((bal >> 48) & 1ull) << 3);
            wmask |= bits << (4 * k);  // bit index 4k+sub

            if (k + 1 < NPASS) { A0 = B0; A1 = B1; }
        }

        // Exact fallback for flagged facts (wave-uniform branch, ~never taken).
        if (wmask) {
            const float4* qa1 = reinterpret_cast<const float4*>(arg1 + (size_t)b * NE);
            const float4* qa2 = reinterpret_cast<const float4*>(arg2 + (size_t)b * NE);
            const float4* fa1 = reinterpret_cast<const float4*>(fact_arg1 + (size_t)b * NF * NE);
            const float4* fa2 = reinterpret_cast<const float4*>(fact_arg2 + (size_t)b * NF * NE);
            const float4 qfr  = qr [lane];
            const float4 qf1  = qa1[lane];
            const float4 qf2  = qa2[lane];
            while (wmask) {
                const int p = __ffs(wmask) - 1;
                wmask &= wmask - 1;
                const size_t base = (size_t)(fbeg + p) * NF4 + lane;
                float acc = sqd4(qfr, fr[base]) + sqd4(qf1, fa1[base]) + sqd4(qf2, fa2[base]);
                #pragma unroll
                for (int s = 1; s < 64; s <<= 1) acc += __shfl_xor(acc, s);
                dmin = fminf(dmin, acc);
            }
        }
    }

    // Per-wave slot write, [slot][b] layout so the finish kernel reads
    // coalesced. No LDS, no barriers; waves retire independently.
    if (lane == 0) ws[(chunk * WAVES_PER_BLOCK + wave) * NB + b] = dmin;
}

// Kernel 2: one tiny block. min over the 64 slots of each b, then exp.
__global__ __launch_bounds__(NB) void nkb_finish_kernel(
    const float* __restrict__ ws,
    float* __restrict__ out)
{
    const int b = threadIdx.x;  // 128 threads
    float m = INFINITY;
    #pragma unroll 8
    for (int s = 0; s < NSLOT; ++s)
        m = fminf(m, ws[s * NB + b]);
    // No candidates anywhere (incl. nb==0): m=+inf -> output exactly 0.
    out[b] = isfinite(m) ? expf(-m) : 0.0f;
}

extern "C" void kernel_launch(void* const* d_in, const int* in_sizes, int n_in,
                              void* d_out, int out_size, void* d_ws, size_t ws_size,
                              hipStream_t stream) {
    const float* rel       = (const float*)d_in[0];
    const float* arg1      = (const float*)d_in[1];
    const float* arg2      = (const float*)d_in[2];
    const float* fact_rel  = (const float*)d_in[3];
    const float* fact_arg1 = (const float*)d_in[4];
    const float* fact_arg2 = (const float*)d_in[5];
    const int*   nb_facts  = (const int*)d_in[6];
    float* out = (float*)d_out;
    float* ws  = (float*)d_ws;

    // 1) prefix screen (512B/fact of fact_rel) + fused exact fallback.
    //    2048 blocks x 4 waves = 32 waves/CU: single residency round.
    const int grid = NB * CHUNKS_PER_B;  // 2048
    nkb_prefix_kernel<<<grid, 256, 0, stream>>>(rel, arg1, arg2,
                                                fact_rel, fact_arg1, fact_arg2,
                                                nb_facts, ws);

    // 2) reduce 64 slots per b, exponentiate.
    nkb_finish_kernel<<<1, NB, 0, stream>>>(ws, out);
}

// Round 7
// 18.904 us; speedup vs baseline: 1.5269x; 1.5269x over previous
//
#include <hip/hip_runtime.h>
#include <math.h>

// Problem constants (match reference)
#define NB 128
#define NF 2048
#define NE 256
#define NF4 (NE / 4)   // 64 float4 per 256-float row

#define WAVES_PER_BLOCK 4
#define FACTS_PER_WAVE 16
#define FACTS_PER_BLOCK 64
#define CHUNKS_PER_B 32
#define NPASS 4                                  // 4 facts per pass, 4 passes
#define NSLOT (CHUNKS_PER_B * WAVES_PER_BLOCK)   // 128 dmin slots per b

// Branch-and-bound threshold. expf(-x) == 0.0f exactly for x > ~104
// (e^-104 < 2^-150 rounds to +0). Squared distance accumulates
// non-negatively over dims, so prefix_d > T => full d > T => score is
// exactly 0.0f in BOTH reference and ours. T=110 leaves margin: any fact
// with a nonzero score has full d <= 104 => prefix <= 104 < 110 => flagged
// and handled by the exact in-wave fallback. At this input distribution the
// 128-dim prefix ~ N(256,32): P(<=110) ~ 2.5e-6 per fact -> fallback ~never
// runs, but correctness never depends on that.
#define THRESH 110.0f

__device__ __forceinline__ float sqd4(float4 a, float4 b) {
    float dx = a.x - b.x;
    float dy = a.y - b.y;
    float dz = a.z - b.z;
    float dw = a.w - b.w;
    return dx * dx + dy * dy + dz * dz + dw * dw;
}

// Kernel 1: stream the first 128 floats (512 B) of each valid fact_rel row.
// 16 lanes per fact (seg = lane&15 covers float4 seg and seg+16), 4 facts
// per pass (sub = lane>>4), 4 fully-unrolled double-buffered passes = 16
// facts per wave (indices clamped to nb-1; clamped duplicates excluded from
// the candidate mask by the f<nb predicate). The wave-uniform candidate mask
// is resolved IN-WAVE: for each (ultra-rare) flagged fact the full 768-dim
// distance is computed exactly (64 lanes x 3 float4 + 6 shuffles) and folded
// into dmin. Every wave (live or dead) writes its dmin slot -> ws fully
// rewritten every call, no init kernel, no atomics.
__global__ __launch_bounds__(256, 8) void nkb_prefix_kernel(
    const float* __restrict__ rel,
    const float* __restrict__ arg1,
    const float* __restrict__ arg2,
    const float* __restrict__ fact_rel,
    const float* __restrict__ fact_arg1,
    const float* __restrict__ fact_arg2,
    const int* __restrict__ nb_facts,
    float* __restrict__ ws)
{
    const int b = blockIdx.x >> 5;        // / CHUNKS_PER_B
    const int chunk = blockIdx.x & 31;    // % CHUNKS_PER_B
    const int nb = nb_facts[b];
    const int tid = threadIdx.x;
    const int wave = tid >> 6;
    const int lane = tid & 63;
    const int sub = lane >> 4;   // which of the 4 facts in a pass
    const int seg = lane & 15;   // float4 segment within the 128-dim prefix

    const int fbeg = chunk * FACTS_PER_BLOCK + wave * FACTS_PER_WAVE;
    float dmin = INFINITY;

    if (fbeg < nb) {
        const int fmax = nb - 1;  // nb >= 1 here
        // Query prefix: 2 float4 = 8 VGPRs (first 128 floats of rel row).
        const float4* qr = reinterpret_cast<const float4*>(rel + (size_t)b * NE);
        const float4 q0 = qr[seg];
        const float4 q1 = qr[seg + 16];

        const float4* fr = reinterpret_cast<const float4*>(fact_rel + (size_t)b * NF * NE);

        unsigned int wmask = 0;  // bit p: fact fbeg+p is a candidate (wave-uniform)
        float4 A0, A1, B0, B1;
        {
            const int f = min(fbeg + sub, fmax);
            const float4* p = fr + (size_t)f * NF4 + seg;
            A0 = p[0];
            A1 = p[16];
        }

        #pragma unroll
        for (int k = 0; k < NPASS; ++k) {
            if (k + 1 < NPASS) {  // double-buffer: next pass's loads in flight
                const int f = min(fbeg + 4 * (k + 1) + sub, fmax);
                const float4* p = fr + (size_t)f * NF4 + seg;
                B0 = p[0];
                B1 = p[16];
            }
            float acc = sqd4(q0, A0) + sqd4(q1, A1);
            // Sum within each 16-lane group: 4 facts reduced simultaneously.
            #pragma unroll
            for (int s = 1; s < 16; s <<= 1) acc += __shfl_xor(acc, s);

            const bool cand = (acc <= THRESH) && (fbeg + 4 * k + sub < nb);
            const unsigned long long bal = __ballot(cand);
            // Group j's verdict sits (replicated) at lanes 16j..16j+15.
            const unsigned int bits =
                  (unsigned int)( (bal        & 1ull)
                               | ((bal >> 16) & 1ull) << 1
                               | ((bal >> 32) & 1ull) << 2
                               | ((bal >> 48) & 1ull) << 3);
            wmask |= bits << (4 * k);  // bit index 4k+sub

            if (k + 1 < NPASS) { A0 = B0; A1 = B1; }
        }

        // Exact fallback for flagged facts (wave-uniform branch, ~never taken).
        if (wmask) {
            const float4* qa1 = reinterpret_cast<const float4*>(arg1 + (size_t)b * NE);
            const float4* qa2 = reinterpret_cast<const float4*>(arg2 + (size_t)b * NE);
            const float4* fa1 = reinterpret_cast<const float4*>(fact_arg1 + (size_t)b * NF * NE);
            const float4* fa2 = reinterpret_cast<const float4*>(fact_arg2 + (size_t)b * NF * NE);
            const float4 qfr  = qr [lane];
            const float4 qf1  = qa1[lane];
            const float4 qf2  = qa2[lane];
            while (wmask) {
                const int p = __ffs(wmask) - 1;
                wmask &= wmask - 1;
                const size_t base = (size_t)(fbeg + p) * NF4 + lane;
                float acc = sqd4(qfr, fr[base]) + sqd4(qf1, fa1[base]) + sqd4(qf2, fa2[base]);
                #pragma unroll
                for (int s = 1; s < 64; s <<= 1) acc += __shfl_xor(acc, s);
                dmin = fminf(dmin, acc);
            }
        }
    }

    // Per-wave slot write, [b][slot] layout: 512B contiguous per b so the
    // finish kernel reduces each b with one coalesced wave-read.
    if (lane == 0) ws[(size_t)b * NSLOT + chunk * WAVES_PER_BLOCK + wave] = dmin;
}

// Kernel 2: one wave per b. Two coalesced loads + 6-shuffle min + exp.
__global__ __launch_bounds__(256) void nkb_finish_kernel(
    const float* __restrict__ ws,
    float* __restrict__ out)
{
    const int wave = threadIdx.x >> 6;
    const int lane = threadIdx.x & 63;
    const int b = blockIdx.x * WAVES_PER_BLOCK + wave;  // 32 blocks x 4 waves

    float m = fminf(ws[(size_t)b * NSLOT + lane],
                    ws[(size_t)b * NSLOT + 64 + lane]);
    #pragma unroll
    for (int s = 1; s < 64; s <<= 1) m = fminf(m, __shfl_xor(m, s));
    if (lane == 0) {
        // No candidates anywhere (incl. nb==0): m=+inf -> output exactly 0.
        out[b] = isfinite(m) ? expf(-m) : 0.0f;
    }
}

extern "C" void kernel_launch(void* const* d_in, const int* in_sizes, int n_in,
                              void* d_out, int out_size, void* d_ws, size_t ws_size,
                              hipStream_t stream) {
    const float* rel       = (const float*)d_in[0];
    const float* arg1      = (const float*)d_in[1];
    const float* arg2      = (const float*)d_in[2];
    const float* fact_rel  = (const float*)d_in[3];
    const float* fact_arg1 = (const float*)d_in[4];
    const float* fact_arg2 = (const float*)d_in[5];
    const int*   nb_facts  = (const int*)d_in[6];
    float* out = (float*)d_out;
    float* ws  = (float*)d_ws;

    // 1) prefix screen (512B/fact of fact_rel) + fused exact fallback.
    const int grid = NB * CHUNKS_PER_B;  // 4096 blocks
    nkb_prefix_kernel<<<grid, 256, 0, stream>>>(rel, arg1, arg2,
                                                fact_rel, fact_arg1, fact_arg2,
                                                nb_facts, ws);

    // 2) wave-parallel reduce of 128 slots per b, exponentiate.
    nkb_finish_kernel<<<NB / WAVES_PER_BLOCK, 256, 0, stream>>>(ws, out);
}

// Round 8
// 16.675 us; speedup vs baseline: 1.7310x; 1.1337x over previous
//
#include <hip/hip_runtime.h>
#include <math.h>

// Problem constants (match reference)
#define NB 128
#define NF 2048
#define NE 256
#define NF4 (NE / 4)   // 64 float4 per 256-float row

#define WAVES_PER_BLOCK 4
#define FACTS_PER_WAVE 16
#define FACTS_PER_BLOCK 64
#define CHUNKS_PER_B 32
#define NPASS 4                                  // 4 facts per pass, 4 passes
#define NSLOT (CHUNKS_PER_B * WAVES_PER_BLOCK)   // 128 dmin slots per b

// Branch-and-bound threshold. expf(-x) == 0.0f exactly for x > ~104
// (e^-104 < 2^-150 rounds to +0). Squared distance accumulates
// non-negatively over dims, so ANY prefix sum > T => full d > T => score is
// exactly 0.0f in BOTH reference and ours. T=110 leaves margin over 104.
// Three stages, each an exact monotone bound (correctness never depends on
// the data distribution, only speed does):
//   A: 64-dim prefix (256 B/row) screens all valid facts  (~21% survive)
//   B: 128-dim prefix (re-reads A's 256 B from cache + 256 B new) (~2e-6)
//   C: full 768-dim exact distance, folded into the running min
#define THRESH 110.0f

__device__ __forceinline__ float sqd4(float4 a, float4 b) {
    float dx = a.x - b.x;
    float dy = a.y - b.y;
    float dz = a.z - b.z;
    float dw = a.w - b.w;
    return dx * dx + dy * dy + dz * dz + dw * dw;
}

// 16 lanes per fact (seg = lane&15), 4 facts per pass (sub = lane>>4),
// 4 fully-unrolled double-buffered stage-A passes = 16 facts per wave
// (indices clamped to nb-1; clamped duplicates excluded from the candidate
// mask by the f<nb predicate). Stage-B candidates are pulled 4-at-a-time
// from the wave-uniform mask. Every wave (live or dead) writes its dmin
// slot -> ws fully rewritten every call, no init kernel, no atomics.
__global__ __launch_bounds__(256, 8) void nkb_prefix_kernel(
    const float* __restrict__ rel,
    const float* __restrict__ arg1,
    const float* __restrict__ arg2,
    const float* __restrict__ fact_rel,
    const float* __restrict__ fact_arg1,
    const float* __restrict__ fact_arg2,
    const int* __restrict__ nb_facts,
    float* __restrict__ ws)
{
    const int b = blockIdx.x >> 5;        // / CHUNKS_PER_B
    const int chunk = blockIdx.x & 31;    // % CHUNKS_PER_B
    const int nb = nb_facts[b];
    const int tid = threadIdx.x;
    const int wave = tid >> 6;
    const int lane = tid & 63;
    const int sub = lane >> 4;   // which of the 4 facts in a pass/batch
    const int seg = lane & 15;   // float4 segment within a 64-dim half-prefix

    const int fbeg = chunk * FACTS_PER_BLOCK + wave * FACTS_PER_WAVE;
    float dmin = INFINITY;

    if (fbeg < nb) {
        const int fmax = nb - 1;  // nb >= 1 here
        // Query prefix: q0 covers dims [4seg,4seg+4) (stage A),
        //               q1 covers dims [64+4seg, 64+4seg+4) (stage B).
        const float4* qr = reinterpret_cast<const float4*>(rel + (size_t)b * NE);
        const float4 q0 = qr[seg];
        const float4 q1 = qr[seg + 16];

        const float4* fr = reinterpret_cast<const float4*>(fact_rel + (size_t)b * NF * NE);

        // ---- Stage A: 64-dim prefix over all 16 facts (256 B/row) ----
        unsigned int maskA = 0;  // bit p: fact fbeg+p survives stage A (uniform)
        float4 A0, B0;
        {
            const int f = min(fbeg + sub, fmax);
            A0 = fr[(size_t)f * NF4 + seg];
        }
        #pragma unroll
        for (int k = 0; k < NPASS; ++k) {
            if (k + 1 < NPASS) {  // double-buffer next pass's load
                const int f = min(fbeg + 4 * (k + 1) + sub, fmax);
                B0 = fr[(size_t)f * NF4 + seg];
            }
            float acc = sqd4(q0, A0);
            #pragma unroll
            for (int s = 1; s < 16; s <<= 1) acc += __shfl_xor(acc, s);

            const bool cand = (acc <= THRESH) && (fbeg + 4 * k + sub < nb);
            const unsigned long long bal = __ballot(cand);
            const unsigned int bits =
                  (unsigned int)( (bal        & 1ull)
                               | ((bal >> 16) & 1ull) << 1
                               | ((bal >> 32) & 1ull) << 2
                               | ((bal >> 48) & 1ull) << 3);
            maskA |= bits << (4 * k);  // bit index 4k+sub

            if (k + 1 < NPASS) A0 = B0;
        }

        // ---- Stage B: 128-dim prefix for stage-A survivors, 4 at a time ----
        unsigned int maskB = 0;  // survivors of the 128-dim screen (uniform)
        while (maskA) {
            unsigned int m = maskA;
            const int i0 = __ffs(m) - 1; m &= m - 1;   // valid (loop guard)
            const int i1 = __ffs(m) - 1; m &= m - 1;   // may be -1
            const int i2 = __ffs(m) - 1; m &= m - 1;
            const int i3 = __ffs(m) - 1; m &= m - 1;
            maskA = m;

            const int idx = (sub == 0) ? i0 : (sub == 1) ? i1 : (sub == 2) ? i2 : i3;
            const bool act = (idx >= 0);
            const int f = fbeg + (act ? idx : i0);  // inactive lanes dup i0 (cache hit)
            const size_t base = (size_t)f * NF4 + seg;
            const float4 P0 = fr[base];        // stage-A bytes: L1/L2 hot
            const float4 P1 = fr[base + 16];   // new 256 B (dims 64..127)
            float acc = sqd4(q0, P0) + sqd4(q1, P1);
            #pragma unroll
            for (int s = 1; s < 16; s <<= 1) acc += __shfl_xor(acc, s);

            const bool candB = act && (acc <= THRESH);
            const unsigned long long bal = __ballot(candB);
            // Map group verdicts back to fact-bit positions (all uniform).
            if ( bal        & 1ull) maskB |= 1u << ((unsigned)i0 & 31u);
            if ((bal >> 16) & 1ull) maskB |= 1u << ((unsigned)i1 & 31u);
            if ((bal >> 32) & 1ull) maskB |= 1u << ((unsigned)i2 & 31u);
            if ((bal >> 48) & 1ull) maskB |= 1u << ((unsigned)i3 & 31u);
        }

        // ---- Stage C: exact full 768-dim distance (wave-uniform, ~never) ----
        if (maskB) {
            const float4* qa1 = reinterpret_cast<const float4*>(arg1 + (size_t)b * NE);
            const float4* qa2 = reinterpret_cast<const float4*>(arg2 + (size_t)b * NE);
            const float4* fa1 = reinterpret_cast<const float4*>(fact_arg1 + (size_t)b * NF * NE);
            const float4* fa2 = reinterpret_cast<const float4*>(fact_arg2 + (size_t)b * NF * NE);
            const float4 qfr  = qr [lane];
            const float4 qf1  = qa1[lane];
            const float4 qf2  = qa2[lane];
            while (maskB) {
                const int p = __ffs(maskB) - 1;
                maskB &= maskB - 1;
                const size_t base = (size_t)(fbeg + p) * NF4 + lane;
                float acc = sqd4(qfr, fr[base]) + sqd4(qf1, fa1[base]) + sqd4(qf2, fa2[base]);
                #pragma unroll
                for (int s = 1; s < 64; s <<= 1) acc += __shfl_xor(acc, s);
                dmin = fminf(dmin, acc);
            }
        }
    }

    // Per-wave slot write, [b][slot] layout: 512B contiguous per b so the
    // finish kernel reduces each b with one coalesced wave-read.
    if (lane == 0) ws[(size_t)b * NSLOT + chunk * WAVES_PER_BLOCK + wave] = dmin;
}

// Kernel 2: one wave per b. Two coalesced loads + 6-shuffle min + exp.
__global__ __launch_bounds__(256) void nkb_finish_kernel(
    const float* __restrict__ ws,
    float* __restrict__ out)
{
    const int wave = threadIdx.x >> 6;
    const int lane = threadIdx.x & 63;
    const int b = blockIdx.x * WAVES_PER_BLOCK + wave;  // 32 blocks x 4 waves

    float m = fminf(ws[(size_t)b * NSLOT + lane],
                    ws[(size_t)b * NSLOT + 64 + lane]);
    #pragma unroll
    for (int s = 1; s < 64; s <<= 1) m = fminf(m, __shfl_xor(m, s));
    if (lane == 0) {
        // No candidates anywhere (incl. nb==0): m=+inf -> output exactly 0.
        out[b] = isfinite(m) ? expf(-m) : 0.0f;
    }
}

extern "C" void kernel_launch(void* const* d_in, const int* in_sizes, int n_in,
                              void* d_out, int out_size, void* d_ws, size_t ws_size,
                              hipStream_t stream) {
    const float* rel       = (const float*)d_in[0];
    const float* arg1      = (const float*)d_in[1];
    const float* arg2      = (const float*)d_in[2];
    const float* fact_rel  = (const float*)d_in[3];
    const float* fact_arg1 = (const float*)d_in[4];
    const float* fact_arg2 = (const float*)d_in[5];
    const int*   nb_facts  = (const int*)d_in[6];
    float* out = (float*)d_out;
    float* ws  = (float*)d_ws;

    // 1) two-stage prefix screen (256B/fact + 256B for ~21% survivors)
    //    with fused exact fallback.
    const int grid = NB * CHUNKS_PER_B;  // 4096 blocks
    nkb_prefix_kernel<<<grid, 256, 0, stream>>>(rel, arg1, arg2,
                                                fact_rel, fact_arg1, fact_arg2,
                                                nb_facts, ws);

    // 2) wave-parallel reduce of 128 slots per b, exponentiate.
    nkb_finish_kernel<<<NB / WAVES_PER_BLOCK, 256, 0, stream>>>(ws, out);
}